// Round 19
// baseline (137.200 us; speedup 1.0000x reference)
//
#include <hip/hip_runtime.h>
#include <cstdint>

typedef short  s16x8 __attribute__((ext_vector_type(8)));
typedef float  f32x4 __attribute__((ext_vector_type(4)));
typedef int    i32x4 __attribute__((ext_vector_type(4)));
typedef int    i32x2 __attribute__((ext_vector_type(2)));
typedef unsigned short u16x4 __attribute__((ext_vector_type(4)));

#define OUT_F 11008
#define IN_F  4096
#define MROWS 512
#define GQ4   176128   // i32x4 elements per W_q row (704512/4)
#define HALF  5504
#define RMOD  172

__device__ __forceinline__ unsigned short f2bf(float f) {
  unsigned u = __builtin_bit_cast(unsigned, f);
  return (unsigned short)((u + 0x8000u) >> 16);
}
__device__ __forceinline__ float bfbits(unsigned bits) {
  return __builtin_bit_cast(float, bits);
}
__device__ __forceinline__ unsigned cvtpk(float a, float b) {
  unsigned r;
  asm("v_cvt_pk_bf16_f32 %0, %1, %2" : "=v"(r) : "v"(a), "v"(b));
  return r;   // lo = bf16(a), hi = bf16(b)
}

// ---- prelude: bf16-convert x and U ----
__global__ __launch_bounds__(256) void convert_k(const float* __restrict__ x,
                                                 const float* __restrict__ U,
                                                 unsigned short* __restrict__ xbf,
                                                 unsigned short* __restrict__ Ubf) {
  int i = blockIdx.x * 256 + threadIdx.x;
  const int NX = (MROWS * IN_F) / 4;
  const int NU = (OUT_F * 32) / 4;
  if (i >= NX + NU) return;
  const float* src; unsigned short* dst; int idx;
  if (i < NX) { src = x; dst = xbf; idx = i; }
  else        { src = U; dst = Ubf; idx = i - NX; }
  f32x4 v = *(const f32x4*)(src + (size_t)idx * 4);
  u16x4 o;
  o[0] = f2bf(v[0]); o[1] = f2bf(v[1]); o[2] = f2bf(v[2]); o[3] = f2bf(v[3]);
  *(u16x4*)(dst + (size_t)idx * 4) = o;
}

// ---- prelude 2: P = x @ V^T (512x32), split-K atomics ----
__global__ __launch_bounds__(256) void pcalc_k(const float* __restrict__ x,
                                               const float* __restrict__ V,
                                               float* __restrict__ P) {
  int m  = (blockIdx.x >> 3) * 8 + (threadIdx.x >> 5);
  int j  = threadIdx.x & 31;
  int k0 = (blockIdx.x & 7) * 512;
  const float* xr = x + (size_t)m * IN_F + k0;
  const float* vr = V + (size_t)j * IN_F + k0;
  float a = 0.f;
#pragma unroll 4
  for (int k = 0; k < 512; k += 4) {
    f32x4 xv = *(const f32x4*)(xr + k);
    f32x4 vv = *(const f32x4*)(vr + k);
    a += xv[0]*vv[0] + xv[1]*vv[1] + xv[2]*vv[2] + xv[3]*vv[3];
  }
  atomicAdd(P + m * 32 + j, a);
}

// ---- fast-path: W dequant to bf16, PRE-SWIZZLED; 4 j-rows per thread ----
// ROUND-19: j = j0 + {0,8,16,24} -- 4 independent Wq read streams + 8 store
// streams per thread (ILP for latency hiding), scale/zero traffic / 4.
// 704,512 threads (2752 blocks). r18 measured the 2-j version at ~57us vs
// a 37us streaming floor; low per-thread ILP was the suspect.
__global__ __launch_bounds__(256) void wdeq_k(const i32x4* __restrict__ Wq4,
                                              const float* __restrict__ scale,
                                              const float* __restrict__ zero,
                                              unsigned short* __restrict__ Wbf) {
  int n   = blockIdx.x * 256 + threadIdx.x;  // 8 j-quads x 88064 chunks
  int j0  = n / 88064;                       // 0..7
  int ch  = n - j0 * 88064;
  int r   = ch >> 9;                         // 0..171
  int chL = ch & 511;
  const int cc0 = ch * 8;
  f32x4 s0 = *(const f32x4*)(scale + cc0);
  f32x4 s1 = *(const f32x4*)(scale + cc0 + 4);
  f32x4 z0 = *(const f32x4*)(zero + cc0);
  f32x4 z1 = *(const f32x4*)(zero + cc0 + 4);
  // issue all 4 Wq stream loads up front for ILP
  i32x4 w0a = Wq4[(size_t)(j0     ) * GQ4 + ch * 2];
  i32x4 w1a = Wq4[(size_t)(j0     ) * GQ4 + ch * 2 + 1];
  i32x4 w0b = Wq4[(size_t)(j0 +  8) * GQ4 + ch * 2];
  i32x4 w1b = Wq4[(size_t)(j0 +  8) * GQ4 + ch * 2 + 1];
  i32x4 w0c = Wq4[(size_t)(j0 + 16) * GQ4 + ch * 2];
  i32x4 w1c = Wq4[(size_t)(j0 + 16) * GQ4 + ch * 2 + 1];
  i32x4 w0d = Wq4[(size_t)(j0 + 24) * GQ4 + ch * 2];
  i32x4 w1d = Wq4[(size_t)(j0 + 24) * GQ4 + ch * 2 + 1];
  float sv[8], mzv[8];
#pragma unroll
  for (int e = 0; e < 4; ++e) {
    sv[e]     = s0[e]; mzv[e]     = -(z0[e] + 128.f) * s0[e];
    sv[e + 4] = s1[e]; mzv[e + 4] = -(z1[e] + 128.f) * s1[e];
  }
#pragma unroll
  for (int p = 0; p < 4; ++p) {
    int j = j0 + p * 8;
    i32x4 w0 = (p == 0) ? w0a : (p == 1) ? w0b : (p == 2) ? w0c : w0d;
    i32x4 w1 = (p == 0) ? w1a : (p == 1) ? w1b : (p == 2) ? w1c : w1d;
    float h[8], l[8];
#pragma unroll
    for (int e = 0; e < 8; ++e) {
      int v = (e < 4) ? w0[e] : w1[e - 4];
      float qh = bfbits(0x43000000u | (((unsigned)v & 0xF0u) << 12));
      float ql = bfbits(0x43000000u | (((unsigned)v & 0x0Fu) << 16));
      h[e] = __builtin_fmaf(qh, sv[e], mzv[e]);
      l[e] = __builtin_fmaf(ql, sv[e], mzv[e]);
    }
    i32x4 hh = { (int)cvtpk(h[0], h[1]), (int)cvtpk(h[2], h[3]),
                 (int)cvtpk(h[4], h[5]), (int)cvtpk(h[6], h[7]) };
    i32x4 ll = { (int)cvtpk(l[0], l[1]), (int)cvtpk(l[2], l[3]),
                 (int)cvtpk(l[4], l[5]), (int)cvtpk(l[6], l[7]) };
    int o  = j * RMOD + r;
    int o2 = o + HALF;
    unsigned sc  = ((unsigned)chL & ~7u) | (((unsigned)chL ^ (unsigned)o)  & 7u);
    unsigned sc2 = ((unsigned)chL & ~7u) | (((unsigned)chL ^ (unsigned)o2) & 7u);
    *(i32x4*)(Wbf + (size_t)o  * IN_F + sc  * 8) = hh;
    *(i32x4*)(Wbf + (size_t)o2 * IN_F + sc2 * 8) = ll;
  }
}

// ---- fast-path GEMM: bf16, tile 64m x 128o, 512 thr (8 waves 2m x 4o) ----
// T4 ring-3 (measured r18: 61.5us, MfmaUtil 32%) -- kept byte-identical.
__global__ __launch_bounds__(512, 4) void gemm_fast(
    const unsigned short* __restrict__ xbf,
    const unsigned short* __restrict__ Wbf,
    const float*          __restrict__ Pf,
    const i32x4*          __restrict__ Ubf4,
    const float*          __restrict__ bias,
    float*                __restrict__ out)
{
  extern __shared__ __align__(16) unsigned short smem[];
  // A ring: smem + k*4096 shorts; B ring: smem + 12288 + k*8192 shorts

  const int tid  = threadIdx.x;
  const int lane = tid & 63;
  const int wid  = tid >> 6;   // 0..7
  const int wm   = wid >> 2;   // 0..1: 32-row m sub-tile
  const int wn   = wid & 3;    // 0..3: 32-row o sub-tile

  const int b  = blockIdx.x;
  const int L  = (b & 7) * 86 + (b >> 3);
  const int gn = L >> 3;          // 0..85  -> o0 = gn*128
  const int gm = L & 7;           // 0..7   -> m0 = gm*64
  const int m0 = gm * 64;
  const int o0 = gn * 128;

  // A staging: pre-swizzled global source, linear LDS dest
  const int arow = tid >> 3;
  const unsigned a_src = (unsigned)(m0 + arow) * IN_F +
                         (((tid & 7) ^ (arow & 7)) * 8);
  // B staging: Wbf already swizzled -> linear source, linear dest
  size_t b_src[2];
#pragma unroll
  for (int it = 0; it < 2; ++it)
    b_src[it] = (size_t)(o0 + it * 64 + (tid >> 3)) * IN_F + (tid & 7) * 8;

  const int akey   = (lane & 7) << 3;
  const int a_base = (wm * 32 + (lane & 15)) * 64 + ((lane >> 4) * 8);
  const int b_base = (wn * 32 + (lane & 15)) * 64 + ((lane >> 4) * 8);

  f32x4 acc[2][2];
  {
    f32x4 zf = {0.f, 0.f, 0.f, 0.f};
#pragma unroll
    for (int i = 0; i < 2; ++i)
#pragma unroll
      for (int j = 0; j < 2; ++j) acc[i][j] = zf;
  }
  f32x4 pf0, pf1; i32x4 uuF;

  auto issueT = [&](int ring, int k0s) {   // 3 VMEM insts per tile
    unsigned short* Adst = smem + ring * 4096;
    unsigned short* Bdst = smem + 12288 + ring * 8192;
    __builtin_amdgcn_global_load_lds(
        (const __attribute__((address_space(1))) unsigned int*)(xbf + a_src + k0s),
        (__attribute__((address_space(3))) unsigned int*)(Adst + tid * 8),
        16, 0, 0);
#pragma unroll
    for (int it = 0; it < 2; ++it) {
      __builtin_amdgcn_global_load_lds(
          (const __attribute__((address_space(1))) unsigned int*)(Wbf + b_src[it] + k0s),
          (__attribute__((address_space(3))) unsigned int*)(Bdst + it * 4096 + tid * 8),
          16, 0, 0);
    }
  };
  auto compute = [&](int ring) {
    const unsigned short* Ac = smem + ring * 4096;
    const unsigned short* Bc = smem + 12288 + ring * 8192;
    __builtin_amdgcn_s_setprio(1);
#pragma unroll
    for (int kk = 0; kk < 64; kk += 32) {
      s16x8 av[2], bv[2];
#pragma unroll
      for (int f = 0; f < 2; ++f)
        av[f] = *(const s16x8*)(Ac + ((a_base + f * 1024 + kk) ^ akey));
#pragma unroll
      for (int f = 0; f < 2; ++f)
        bv[f] = *(const s16x8*)(Bc + ((b_base + f * 1024 + kk) ^ akey));
#pragma unroll
      for (int i = 0; i < 2; ++i)
#pragma unroll
        for (int j = 0; j < 2; ++j)
          acc[i][j] = __builtin_amdgcn_mfma_f32_16x16x32_bf16(av[i], bv[j], acc[i][j], 0, 0, 0);
    }
    __builtin_amdgcn_s_setprio(0);
  };
  auto loadF = [&]() {
    int row = tid >> 3, h8 = tid & 7;
    if (h8 < 4) {
      pf0 = *(const f32x4*)(Pf + (m0 + row) * 32 + h8 * 8);
      pf1 = *(const f32x4*)(Pf + (m0 + row) * 32 + h8 * 8 + 4);
    }
    int rw = tid >> 2, h4 = tid & 3;
    uuF = Ubf4[(size_t)(o0 + rw) * 4 + h4];
  };
  auto writeF = [&](int ring) {
    unsigned short* An = smem + ring * 4096;
    unsigned short* Bn = smem + 12288 + ring * 8192;
    i32x4 zi = {0, 0, 0, 0};
    {
      int row = tid >> 3, h8 = tid & 7, key = row & 7;
      i32x4 v = zi;
      if (h8 < 4)
        v = i32x4{ (int)cvtpk(pf0[0], pf0[1]), (int)cvtpk(pf0[2], pf0[3]),
                   (int)cvtpk(pf1[0], pf1[1]), (int)cvtpk(pf1[2], pf1[3]) };
      *(i32x4*)(An + row * 64 + ((h8 ^ key) * 8)) = v;
    }
    {
      int rw = tid >> 2, h4 = tid & 3, key = rw & 7;
      *(i32x4*)(Bn + rw * 64 + ((h4 ^ key) * 8))       = uuF;
      *(i32x4*)(Bn + rw * 64 + (((h4 + 4) ^ key) * 8)) = zi;
    }
  };

#define WAIT_LGKM0 asm volatile("s_waitcnt lgkmcnt(0)" ::: "memory")
#define WAIT_VM(N) asm volatile("s_waitcnt vmcnt(" #N ")" ::: "memory")
#define BAR        __builtin_amdgcn_s_barrier()

  // ---- prologue: tiles 0,1 staged; tile 1's loads stay in flight ----
  issueT(0, 0);
  issueT(1, 64);
  WAIT_VM(3);
  BAR;

#define STEP(RB, TI, IB) \
  issueT(IB, (TI) * 64); compute(RB); WAIT_LGKM0; WAIT_VM(3); BAR;

  for (int t3 = 0; t3 < 60; t3 += 3) {
    STEP(0, t3 + 2, 2)
    STEP(1, t3 + 3, 0)
    STEP(2, t3 + 4, 1)
  }
  STEP(0, 62, 2)   // compute tile 60, issue 62
  STEP(1, 63, 0)   // compute tile 61, issue 63
  compute(2); WAIT_LGKM0; WAIT_VM(0); BAR;
  loadF();
  compute(0);
  writeF(1);
  WAIT_LGKM0; BAR;
  compute(1);

#undef STEP
#undef WAIT_LGKM0
#undef WAIT_VM
#undef BAR

  // ---- epilogue: bias + store (Wbf in final row order) ----
#pragma unroll
  for (int fn = 0; fn < 2; ++fn) {
    int o = o0 + wn * 32 + fn * 16 + (lane & 15);
    float bv = bias[o];
#pragma unroll
    for (int fm = 0; fm < 2; ++fm) {
      int m = m0 + wm * 32 + fm * 16 + ((lane >> 4) << 2);
#pragma unroll
      for (int j = 0; j < 4; ++j)
        out[(size_t)(m + j) * OUT_F + o] = acc[fm][fn][j] + bv;
    }
  }
}

// ================= slow-path fallback (ws too small): round-8 kernels ======
__global__ __launch_bounds__(256) void mz_k(const float* __restrict__ scale,
                                            const float* __restrict__ zero,
                                            f32x4* __restrict__ mz) {
  int idx = blockIdx.x * 256 + threadIdx.x;
  if (idx >= 176128) return;
  f32x4 s = *(const f32x4*)(scale + (size_t)idx * 4);
  f32x4 z = *(const f32x4*)(zero  + (size_t)idx * 4);
  f32x4 m;
#pragma unroll
  for (int e = 0; e < 4; ++e) m[e] = -(z[e] + 128.f) * s[e];
  mz[idx] = m;
}

__global__ __launch_bounds__(512, 6) void milo_gemm(
    const unsigned short* __restrict__ xbf,
    const i32x4*          __restrict__ Wq4,
    const f32x4*          __restrict__ Sc4,
    const f32x4*          __restrict__ Mz4,
    const float*          __restrict__ Pf,
    const i32x4*          __restrict__ Ubf4,
    const float*          __restrict__ bias,
    float*                __restrict__ out)
{
  extern __shared__ __align__(16) unsigned short smem[];
  const int tid  = threadIdx.x;
  const int lane = tid & 63;
  const int wid  = tid >> 6;
  const int wm   = wid >> 1;
  const int wn   = wid & 1;
  const int b  = blockIdx.x;
  const int L  = (b & 7) * 86 + (b >> 3);
  const int gn = L >> 2;
  const int gm = L & 3;
  const int m0 = gm * 128;
  const int o0 = gn * 32;
  const int tr = tid >> 4;
  unsigned wq_off, sc_off;
  {
    int o = o0 + tr;
    int g = o / RMOD;
    int r = o - g * RMOD;
    wq_off = (unsigned)g * GQ4 + (unsigned)r * 1024u + (tid & 15);
    sc_off = (unsigned)r * 1024u + (tid & 15);
  }
  unsigned a_src[2];
#pragma unroll
  for (int it = 0; it < 2; ++it) {
    int row   = wid * 16 + it * 8 + (lane >> 3);
    int chunk = (lane & 7) ^ (lane >> 3);
    a_src[it] = (unsigned)(m0 + row) * IN_F + chunk * 8;
  }
  const int akey   = (lane & 7) << 3;
  const int a_base = (wm * 32 + (lane & 15)) * 64 + ((lane >> 4) * 8);
  const int b_base = (wn * 32 + (lane & 15)) * 64 + ((lane >> 4) * 8);
  f32x4 acc[2][2];
  {
    f32x4 zf = {0.f, 0.f, 0.f, 0.f};
#pragma unroll
    for (int i = 0; i < 2; ++i)
#pragma unroll
      for (int j = 0; j < 2; ++j) acc[i][j] = zf;
  }
  i32x4 wq; f32x4 s4, mz4;
  f32x4 pf[2]; i32x4 uuF;
  auto issueA = [&](int buf, int k0s) {
    unsigned short* Adst = smem + buf * 8192;
#pragma unroll
    for (int it = 0; it < 2; ++it) {
      __builtin_amdgcn_global_load_lds(
          (const __attribute__((address_space(1))) unsigned int*)(xbf + a_src[it] + k0s),
          (__attribute__((address_space(3))) unsigned int*)(Adst + (wid * 16 + it * 8) * 64),
          16, 0, 0);
    }
  };
  auto loadB = [&](int kq) {
    wq  = Wq4[wq_off + kq];
    s4  = Sc4[sc_off + kq];
    mz4 = Mz4[sc_off + kq];
  };
  auto writeB = [&](int buf) {
    unsigned short* Bn = smem + 16384 + buf * 4096;
    int scol = ((tid & 15) * 4) ^ ((tr & 7) << 3);
    float h[4], l[4];
#pragma unroll
    for (int e = 0; e < 4; ++e) {
      int v = wq[e];
      float qh = bfbits(0x43000000u | (((unsigned)v & 0xF0u) << 12));
      float ql = bfbits(0x43000000u | (((unsigned)v & 0x0Fu) << 16));
      h[e] = __builtin_fmaf(qh, s4[e], mz4[e]);
      l[e] = __builtin_fmaf(ql, s4[e], mz4[e]);
    }
    i32x2 hh = { (int)cvtpk(h[0], h[1]), (int)cvtpk(h[2], h[3]) };
    i32x2 ll = { (int)cvtpk(l[0], l[1]), (int)cvtpk(l[2], l[3]) };
    *(i32x2*)(Bn + tr * 64 + scol)        = hh;
    *(i32x2*)(Bn + (tr + 32) * 64 + scol) = ll;
  };
  auto loadF = [&]() {
    int row = tid >> 2, h4 = tid & 3;
#pragma unroll
    for (int q = 0; q < 2; ++q)
      pf[q] = *(const f32x4*)(Pf + (m0 + row) * 32 + h4 * 8 + q * 4);
    int rw = tid >> 3, h8 = tid & 7;
    int oc = (rw < 32) ? (o0 + rw) : (HALF + o0 + rw - 32);
    uuF = Ubf4[oc * 4 + (h8 & 3)];
  };
  auto writeF = [&](int buf) {
    unsigned short* An = smem + buf * 8192;
    unsigned short* Bn = smem + 16384 + buf * 4096;
    i32x4 zi = {0, 0, 0, 0};
    {
      int row = tid >> 2, h4 = tid & 3;
      int key = (row & 7) << 3;
      i32x4 t4 = { (int)cvtpk(pf[0][0], pf[0][1]), (int)cvtpk(pf[0][2], pf[0][3]),
                   (int)cvtpk(pf[1][0], pf[1][1]), (int)cvtpk(pf[1][2], pf[1][3]) };
      *(i32x4*)(An + row * 64 + ((h4 * 8) ^ key))      = t4;
      *(i32x4*)(An + row * 64 + ((32 + h4 * 8) ^ key)) = zi;
    }
    {
      int rw = tid >> 3, h8 = tid & 7;
      int key = (rw & 7) << 3;
      *(i32x4*)(Bn + rw * 64 + ((h8 * 8) ^ key)) = (h8 < 4) ? uuF : zi;
    }
  };
  auto compute = [&](int buf) {
    const unsigned short* Ac = smem + buf * 8192;
    const unsigned short* Bc = smem + 16384 + buf * 4096;
    __builtin_amdgcn_s_setprio(1);
#pragma unroll
    for (int kk = 0; kk < 64; kk += 32) {
      s16x8 av[2], bv[2];
#pragma unroll
      for (int f = 0; f < 2; ++f)
        av[f] = *(const s16x8*)(Ac + ((a_base + f * 1024 + kk) ^ akey));
#pragma unroll
      for (int f = 0; f < 2; ++f)
        bv[f] = *(const s16x8*)(Bc + ((b_base + f * 1024 + kk) ^ akey));
#pragma unroll
      for (int i = 0; i < 2; ++i)
#pragma unroll
        for (int j = 0; j < 2; ++j)
          acc[i][j] = __builtin_amdgcn_mfma_f32_16x16x32_bf16(av[i], bv[j], acc[i][j], 0, 0, 0);
    }
    __builtin_amdgcn_s_setprio(0);
  };
  loadB(0);
  issueA(0, 0);
  writeB(0);
  __syncthreads();
  for (int t = 0; t < 63; ++t) {
    int cur = t & 1, nxt = cur ^ 1;
    loadB((t + 1) * 16);
    issueA(nxt, (t + 1) * 64);
    compute(cur);
    writeB(nxt);
    __syncthreads();
  }
  loadF();
  compute(1);
  writeF(0);
  __syncthreads();
  compute(0);
#pragma unroll
  for (int fn = 0; fn < 2; ++fn) {
    int c = wn * 32 + fn * 16 + (lane & 15);
    int o = (c < 32) ? (o0 + c) : (HALF + o0 + (c - 32));
    float bv = bias[o];
#pragma unroll
    for (int fm = 0; fm < 2; ++fm) {
      int m = m0 + wm * 32 + fm * 16 + ((lane >> 4) << 2);
#pragma unroll
      for (int j = 0; j < 4; ++j)
        out[(size_t)(m + j) * OUT_F + o] = acc[fm][fn][j] + bv;
    }
  }
}

extern "C" void kernel_launch(void* const* d_in, const int* in_sizes, int n_in,
                              void* d_out, int out_size, void* d_ws, size_t ws_size,
                              hipStream_t stream) {
  const float* x     = (const float*)d_in[0];
  const int*   Wq    = (const int*)d_in[1];
  const float* scale = (const float*)d_in[2];
  const float* zero  = (const float*)d_in[3];
  const float* U     = (const float*)d_in[4];
  const float* V     = (const float*)d_in[5];
  const float* bias  = (const float*)d_in[6];
  float* out = (float*)d_out;

  unsigned short* xbf = (unsigned short*)d_ws;                 // 4 MB
  unsigned short* Ubf = xbf + (size_t)MROWS * IN_F;            // 704 KB
  float*          P   = (float*)(Ubf + (size_t)OUT_F * 32);    // 64 KB
  char*           rest = (char*)(P + (size_t)MROWS * 32);
  const size_t base   = (size_t)MROWS * IN_F * 2 + (size_t)OUT_F * 32 * 2
                      + (size_t)MROWS * 32 * 4;                // 4,964,352
  const size_t wbf_sz = (size_t)OUT_F * IN_F * 2;              // 90,177,536

  (void)hipMemsetAsync(P, 0, (size_t)MROWS * 32 * sizeof(float), stream);
  convert_k<<<2392, 256, 0, stream>>>(x, U, xbf, Ubf);
  pcalc_k<<<512, 256, 0, stream>>>(x, V, P);

  if (ws_size >= base + wbf_sz) {
    // ---- fast path: streaming dequant (4-j ILP) + T4-pipelined bf16 GEMM
    unsigned short* Wbf = (unsigned short*)rest;
    wdeq_k<<<2752, 256, 0, stream>>>((const i32x4*)Wq, scale, zero, Wbf);
    gemm_fast<<<688, 512, 73728, stream>>>(xbf, Wbf, P, (const i32x4*)Ubf,
                                           bias, out);
  } else {
    // ---- slow path: round-8 fused dequant GEMM (known-good)
    float* mz = (float*)rest;
    mz_k<<<688, 256, 0, stream>>>(scale, zero, (f32x4*)mz);
    milo_gemm<<<688, 512, 49152, stream>>>(xbf, (const i32x4*)Wq,
                                           (const f32x4*)scale, (const f32x4*)mz,
                                           P, (const i32x4*)Ubf, bias, out);
  }
}

// Round 20
// 135.205 us; speedup vs baseline: 1.0148x; 1.0148x over previous
//
#include <hip/hip_runtime.h>
#include <cstdint>

typedef short  s16x8 __attribute__((ext_vector_type(8)));
typedef float  f32x4 __attribute__((ext_vector_type(4)));
typedef int    i32x4 __attribute__((ext_vector_type(4)));
typedef int    i32x2 __attribute__((ext_vector_type(2)));
typedef unsigned short u16x4 __attribute__((ext_vector_type(4)));

#define OUT_F 11008
#define IN_F  4096
#define MROWS 512
#define GQ4   176128   // i32x4 elements per W_q row (704512/4)
#define HALF  5504
#define RMOD  172

__device__ __forceinline__ unsigned short f2bf(float f) {
  unsigned u = __builtin_bit_cast(unsigned, f);
  return (unsigned short)((u + 0x8000u) >> 16);
}
__device__ __forceinline__ float bfbits(unsigned bits) {
  return __builtin_bit_cast(float, bits);
}
__device__ __forceinline__ unsigned cvtpk(float a, float b) {
  unsigned r;
  asm("v_cvt_pk_bf16_f32 %0, %1, %2" : "=v"(r) : "v"(a), "v"(b));
  return r;   // lo = bf16(a), hi = bf16(b)
}

// ---- prelude: bf16-convert x and U ----
__global__ __launch_bounds__(256) void convert_k(const float* __restrict__ x,
                                                 const float* __restrict__ U,
                                                 unsigned short* __restrict__ xbf,
                                                 unsigned short* __restrict__ Ubf) {
  int i = blockIdx.x * 256 + threadIdx.x;
  const int NX = (MROWS * IN_F) / 4;
  const int NU = (OUT_F * 32) / 4;
  if (i >= NX + NU) return;
  const float* src; unsigned short* dst; int idx;
  if (i < NX) { src = x; dst = xbf; idx = i; }
  else        { src = U; dst = Ubf; idx = i - NX; }
  f32x4 v = *(const f32x4*)(src + (size_t)idx * 4);
  u16x4 o;
  o[0] = f2bf(v[0]); o[1] = f2bf(v[1]); o[2] = f2bf(v[2]); o[3] = f2bf(v[3]);
  *(u16x4*)(dst + (size_t)idx * 4) = o;
}

// ---- prelude 2: P = x @ V^T (512x32), split-K atomics ----
__global__ __launch_bounds__(256) void pcalc_k(const float* __restrict__ x,
                                               const float* __restrict__ V,
                                               float* __restrict__ P) {
  int m  = (blockIdx.x >> 3) * 8 + (threadIdx.x >> 5);
  int j  = threadIdx.x & 31;
  int k0 = (blockIdx.x & 7) * 512;
  const float* xr = x + (size_t)m * IN_F + k0;
  const float* vr = V + (size_t)j * IN_F + k0;
  float a = 0.f;
#pragma unroll 4
  for (int k = 0; k < 512; k += 4) {
    f32x4 xv = *(const f32x4*)(xr + k);
    f32x4 vv = *(const f32x4*)(vr + k);
    a += xv[0]*vv[0] + xv[1]*vv[1] + xv[2]*vv[2] + xv[3]*vv[3];
  }
  atomicAdd(P + m * 32 + j, a);
}

// ---- fast-path: W dequant to bf16, PRE-SWIZZLED; 2 j-rows per thread ----
// Measured r18: ~50us vs 44us BW floor (276 MB round-trip) -- near-optimal.
// r19's 4-j ILP variant was neutral-to-negative; reverted to this config.
__global__ __launch_bounds__(256) void wdeq_k(const i32x4* __restrict__ Wq4,
                                              const float* __restrict__ scale,
                                              const float* __restrict__ zero,
                                              unsigned short* __restrict__ Wbf) {
  int n   = blockIdx.x * 256 + threadIdx.x;  // 16 j-pairs x 88064 chunks
  int j0  = n / 88064;                       // 0..15
  int ch  = n - j0 * 88064;
  int r   = ch >> 9;                         // 0..171
  int chL = ch & 511;
  const int cc0 = ch * 8;
  f32x4 s0 = *(const f32x4*)(scale + cc0);
  f32x4 s1 = *(const f32x4*)(scale + cc0 + 4);
  f32x4 z0 = *(const f32x4*)(zero + cc0);
  f32x4 z1 = *(const f32x4*)(zero + cc0 + 4);
  float sv[8], mzv[8];
#pragma unroll
  for (int e = 0; e < 4; ++e) {
    sv[e]     = s0[e]; mzv[e]     = -(z0[e] + 128.f) * s0[e];
    sv[e + 4] = s1[e]; mzv[e + 4] = -(z1[e] + 128.f) * s1[e];
  }
#pragma unroll
  for (int p = 0; p < 2; ++p) {
    int j = j0 + p * 16;
    i32x4 w0 = Wq4[(size_t)j * GQ4 + ch * 2];
    i32x4 w1 = Wq4[(size_t)j * GQ4 + ch * 2 + 1];
    float h[8], l[8];
#pragma unroll
    for (int e = 0; e < 8; ++e) {
      int v = (e < 4) ? w0[e] : w1[e - 4];
      float qh = bfbits(0x43000000u | (((unsigned)v & 0xF0u) << 12));
      float ql = bfbits(0x43000000u | (((unsigned)v & 0x0Fu) << 16));
      h[e] = __builtin_fmaf(qh, sv[e], mzv[e]);
      l[e] = __builtin_fmaf(ql, sv[e], mzv[e]);
    }
    i32x4 hh = { (int)cvtpk(h[0], h[1]), (int)cvtpk(h[2], h[3]),
                 (int)cvtpk(h[4], h[5]), (int)cvtpk(h[6], h[7]) };
    i32x4 ll = { (int)cvtpk(l[0], l[1]), (int)cvtpk(l[2], l[3]),
                 (int)cvtpk(l[4], l[5]), (int)cvtpk(l[6], l[7]) };
    int o  = j * RMOD + r;
    int o2 = o + HALF;
    unsigned sc  = ((unsigned)chL & ~7u) | (((unsigned)chL ^ (unsigned)o)  & 7u);
    unsigned sc2 = ((unsigned)chL & ~7u) | (((unsigned)chL ^ (unsigned)o2) & 7u);
    *(i32x4*)(Wbf + (size_t)o  * IN_F + sc  * 8) = hh;
    *(i32x4*)(Wbf + (size_t)o2 * IN_F + sc2 * 8) = ll;
  }
}

// ---- fast-path GEMM: bf16, tile 64m x 128o, 512 thr (8 waves 2m x 4o) ----
// T4 ring-3 (measured r18: 61.5us, MfmaUtil 32%, 751 TF effective).
__global__ __launch_bounds__(512, 4) void gemm_fast(
    const unsigned short* __restrict__ xbf,
    const unsigned short* __restrict__ Wbf,
    const float*          __restrict__ Pf,
    const i32x4*          __restrict__ Ubf4,
    const float*          __restrict__ bias,
    float*                __restrict__ out)
{
  extern __shared__ __align__(16) unsigned short smem[];
  // A ring: smem + k*4096 shorts; B ring: smem + 12288 + k*8192 shorts

  const int tid  = threadIdx.x;
  const int lane = tid & 63;
  const int wid  = tid >> 6;   // 0..7
  const int wm   = wid >> 2;   // 0..1: 32-row m sub-tile
  const int wn   = wid & 3;    // 0..3: 32-row o sub-tile

  const int b  = blockIdx.x;
  const int L  = (b & 7) * 86 + (b >> 3);
  const int gn = L >> 3;          // 0..85  -> o0 = gn*128
  const int gm = L & 7;           // 0..7   -> m0 = gm*64
  const int m0 = gm * 64;
  const int o0 = gn * 128;

  // A staging: pre-swizzled global source, linear LDS dest
  const int arow = tid >> 3;
  const unsigned a_src = (unsigned)(m0 + arow) * IN_F +
                         (((tid & 7) ^ (arow & 7)) * 8);
  // B staging: Wbf already swizzled -> linear source, linear dest
  size_t b_src[2];
#pragma unroll
  for (int it = 0; it < 2; ++it)
    b_src[it] = (size_t)(o0 + it * 64 + (tid >> 3)) * IN_F + (tid & 7) * 8;

  const int akey   = (lane & 7) << 3;
  const int a_base = (wm * 32 + (lane & 15)) * 64 + ((lane >> 4) * 8);
  const int b_base = (wn * 32 + (lane & 15)) * 64 + ((lane >> 4) * 8);

  f32x4 acc[2][2];
  {
    f32x4 zf = {0.f, 0.f, 0.f, 0.f};
#pragma unroll
    for (int i = 0; i < 2; ++i)
#pragma unroll
      for (int j = 0; j < 2; ++j) acc[i][j] = zf;
  }
  f32x4 pf0, pf1; i32x4 uuF;

  auto issueT = [&](int ring, int k0s) {   // 3 VMEM insts per tile
    unsigned short* Adst = smem + ring * 4096;
    unsigned short* Bdst = smem + 12288 + ring * 8192;
    __builtin_amdgcn_global_load_lds(
        (const __attribute__((address_space(1))) unsigned int*)(xbf + a_src + k0s),
        (__attribute__((address_space(3))) unsigned int*)(Adst + tid * 8),
        16, 0, 0);
#pragma unroll
    for (int it = 0; it < 2; ++it) {
      __builtin_amdgcn_global_load_lds(
          (const __attribute__((address_space(1))) unsigned int*)(Wbf + b_src[it] + k0s),
          (__attribute__((address_space(3))) unsigned int*)(Bdst + it * 4096 + tid * 8),
          16, 0, 0);
    }
  };
  auto compute = [&](int ring) {
    const unsigned short* Ac = smem + ring * 4096;
    const unsigned short* Bc = smem + 12288 + ring * 8192;
    __builtin_amdgcn_s_setprio(1);
#pragma unroll
    for (int kk = 0; kk < 64; kk += 32) {
      s16x8 av[2], bv[2];
#pragma unroll
      for (int f = 0; f < 2; ++f)
        av[f] = *(const s16x8*)(Ac + ((a_base + f * 1024 + kk) ^ akey));
#pragma unroll
      for (int f = 0; f < 2; ++f)
        bv[f] = *(const s16x8*)(Bc + ((b_base + f * 1024 + kk) ^ akey));
#pragma unroll
      for (int i = 0; i < 2; ++i)
#pragma unroll
        for (int j = 0; j < 2; ++j)
          acc[i][j] = __builtin_amdgcn_mfma_f32_16x16x32_bf16(av[i], bv[j], acc[i][j], 0, 0, 0);
    }
    __builtin_amdgcn_s_setprio(0);
  };
  auto loadF = [&]() {
    int row = tid >> 3, h8 = tid & 7;
    if (h8 < 4) {
      pf0 = *(const f32x4*)(Pf + (m0 + row) * 32 + h8 * 8);
      pf1 = *(const f32x4*)(Pf + (m0 + row) * 32 + h8 * 8 + 4);
    }
    int rw = tid >> 2, h4 = tid & 3;
    uuF = Ubf4[(size_t)(o0 + rw) * 4 + h4];
  };
  auto writeF = [&](int ring) {
    unsigned short* An = smem + ring * 4096;
    unsigned short* Bn = smem + 12288 + ring * 8192;
    i32x4 zi = {0, 0, 0, 0};
    {
      int row = tid >> 3, h8 = tid & 7, key = row & 7;
      i32x4 v = zi;
      if (h8 < 4)
        v = i32x4{ (int)cvtpk(pf0[0], pf0[1]), (int)cvtpk(pf0[2], pf0[3]),
                   (int)cvtpk(pf1[0], pf1[1]), (int)cvtpk(pf1[2], pf1[3]) };
      *(i32x4*)(An + row * 64 + ((h8 ^ key) * 8)) = v;
    }
    {
      int rw = tid >> 2, h4 = tid & 3, key = rw & 7;
      *(i32x4*)(Bn + rw * 64 + ((h4 ^ key) * 8))       = uuF;
      *(i32x4*)(Bn + rw * 64 + (((h4 + 4) ^ key) * 8)) = zi;
    }
  };

#define WAIT_LGKM0 asm volatile("s_waitcnt lgkmcnt(0)" ::: "memory")
#define WAIT_VM(N) asm volatile("s_waitcnt vmcnt(" #N ")" ::: "memory")
#define BAR        __builtin_amdgcn_s_barrier()

  // ---- prologue: tiles 0,1 staged; tile 1's loads stay in flight ----
  issueT(0, 0);
  issueT(1, 64);
  WAIT_VM(3);
  BAR;

#define STEP(RB, TI, IB) \
  issueT(IB, (TI) * 64); compute(RB); WAIT_LGKM0; WAIT_VM(3); BAR;

  for (int t3 = 0; t3 < 60; t3 += 3) {
    STEP(0, t3 + 2, 2)
    STEP(1, t3 + 3, 0)
    STEP(2, t3 + 4, 1)
  }
  STEP(0, 62, 2)   // compute tile 60, issue 62
  STEP(1, 63, 0)   // compute tile 61, issue 63
  compute(2); WAIT_LGKM0; WAIT_VM(0); BAR;
  loadF();
  compute(0);
  writeF(1);
  WAIT_LGKM0; BAR;
  compute(1);

#undef STEP
#undef WAIT_LGKM0
#undef WAIT_VM
#undef BAR

  // ---- epilogue: bias + store (Wbf in final row order) ----
#pragma unroll
  for (int fn = 0; fn < 2; ++fn) {
    int o = o0 + wn * 32 + fn * 16 + (lane & 15);
    float bv = bias[o];
#pragma unroll
    for (int fm = 0; fm < 2; ++fm) {
      int m = m0 + wm * 32 + fm * 16 + ((lane >> 4) << 2);
#pragma unroll
      for (int j = 0; j < 4; ++j)
        out[(size_t)(m + j) * OUT_F + o] = acc[fm][fn][j] + bv;
    }
  }
}

// ================= slow-path fallback (ws too small): round-8 kernels ======
__global__ __launch_bounds__(256) void mz_k(const float* __restrict__ scale,
                                            const float* __restrict__ zero,
                                            f32x4* __restrict__ mz) {
  int idx = blockIdx.x * 256 + threadIdx.x;
  if (idx >= 176128) return;
  f32x4 s = *(const f32x4*)(scale + (size_t)idx * 4);
  f32x4 z = *(const f32x4*)(zero  + (size_t)idx * 4);
  f32x4 m;
#pragma unroll
  for (int e = 0; e < 4; ++e) m[e] = -(z[e] + 128.f) * s[e];
  mz[idx] = m;
}

__global__ __launch_bounds__(512, 6) void milo_gemm(
    const unsigned short* __restrict__ xbf,
    const i32x4*          __restrict__ Wq4,
    const f32x4*          __restrict__ Sc4,
    const f32x4*          __restrict__ Mz4,
    const float*          __restrict__ Pf,
    const i32x4*          __restrict__ Ubf4,
    const float*          __restrict__ bias,
    float*                __restrict__ out)
{
  extern __shared__ __align__(16) unsigned short smem[];
  const int tid  = threadIdx.x;
  const int lane = tid & 63;
  const int wid  = tid >> 6;
  const int wm   = wid >> 1;
  const int wn   = wid & 1;
  const int b  = blockIdx.x;
  const int L  = (b & 7) * 86 + (b >> 3);
  const int gn = L >> 2;
  const int gm = L & 3;
  const int m0 = gm * 128;
  const int o0 = gn * 32;
  const int tr = tid >> 4;
  unsigned wq_off, sc_off;
  {
    int o = o0 + tr;
    int g = o / RMOD;
    int r = o - g * RMOD;
    wq_off = (unsigned)g * GQ4 + (unsigned)r * 1024u + (tid & 15);
    sc_off = (unsigned)r * 1024u + (tid & 15);
  }
  unsigned a_src[2];
#pragma unroll
  for (int it = 0; it < 2; ++it) {
    int row   = wid * 16 + it * 8 + (lane >> 3);
    int chunk = (lane & 7) ^ (lane >> 3);
    a_src[it] = (unsigned)(m0 + row) * IN_F + chunk * 8;
  }
  const int akey   = (lane & 7) << 3;
  const int a_base = (wm * 32 + (lane & 15)) * 64 + ((lane >> 4) * 8);
  const int b_base = (wn * 32 + (lane & 15)) * 64 + ((lane >> 4) * 8);
  f32x4 acc[2][2];
  {
    f32x4 zf = {0.f, 0.f, 0.f, 0.f};
#pragma unroll
    for (int i = 0; i < 2; ++i)
#pragma unroll
      for (int j = 0; j < 2; ++j) acc[i][j] = zf;
  }
  i32x4 wq; f32x4 s4, mz4;
  f32x4 pf[2]; i32x4 uuF;
  auto issueA = [&](int buf, int k0s) {
    unsigned short* Adst = smem + buf * 8192;
#pragma unroll
    for (int it = 0; it < 2; ++it) {
      __builtin_amdgcn_global_load_lds(
          (const __attribute__((address_space(1))) unsigned int*)(xbf + a_src[it] + k0s),
          (__attribute__((address_space(3))) unsigned int*)(Adst + (wid * 16 + it * 8) * 64),
          16, 0, 0);
    }
  };
  auto loadB = [&](int kq) {
    wq  = Wq4[wq_off + kq];
    s4  = Sc4[sc_off + kq];
    mz4 = Mz4[sc_off + kq];
  };
  auto writeB = [&](int buf) {
    unsigned short* Bn = smem + 16384 + buf * 4096;
    int scol = ((tid & 15) * 4) ^ ((tr & 7) << 3);
    float h[4], l[4];
#pragma unroll
    for (int e = 0; e < 4; ++e) {
      int v = wq[e];
      float qh = bfbits(0x43000000u | (((unsigned)v & 0xF0u) << 12));
      float ql = bfbits(0x43000000u | (((unsigned)v & 0x0Fu) << 16));
      h[e] = __builtin_fmaf(qh, s4[e], mz4[e]);
      l[e] = __builtin_fmaf(ql, s4[e], mz4[e]);
    }
    i32x2 hh = { (int)cvtpk(h[0], h[1]), (int)cvtpk(h[2], h[3]) };
    i32x2 ll = { (int)cvtpk(l[0], l[1]), (int)cvtpk(l[2], l[3]) };
    *(i32x2*)(Bn + tr * 64 + scol)        = hh;
    *(i32x2*)(Bn + (tr + 32) * 64 + scol) = ll;
  };
  auto loadF = [&]() {
    int row = tid >> 2, h4 = tid & 3;
#pragma unroll
    for (int q = 0; q < 2; ++q)
      pf[q] = *(const f32x4*)(Pf + (m0 + row) * 32 + h4 * 8 + q * 4);
    int rw = tid >> 3, h8 = tid & 7;
    int oc = (rw < 32) ? (o0 + rw) : (HALF + o0 + rw - 32);
    uuF = Ubf4[oc * 4 + (h8 & 3)];
  };
  auto writeF = [&](int buf) {
    unsigned short* An = smem + buf * 8192;
    unsigned short* Bn = smem + 16384 + buf * 4096;
    i32x4 zi = {0, 0, 0, 0};
    {
      int row = tid >> 2, h4 = tid & 3;
      int key = (row & 7) << 3;
      i32x4 t4 = { (int)cvtpk(pf[0][0], pf[0][1]), (int)cvtpk(pf[0][2], pf[0][3]),
                   (int)cvtpk(pf[1][0], pf[1][1]), (int)cvtpk(pf[1][2], pf[1][3]) };
      *(i32x4*)(An + row * 64 + ((h4 * 8) ^ key))      = t4;
      *(i32x4*)(An + row * 64 + ((32 + h4 * 8) ^ key)) = zi;
    }
    {
      int rw = tid >> 3, h8 = tid & 7;
      int key = (rw & 7) << 3;
      *(i32x4*)(Bn + rw * 64 + ((h8 * 8) ^ key)) = (h8 < 4) ? uuF : zi;
    }
  };
  auto compute = [&](int buf) {
    const unsigned short* Ac = smem + buf * 8192;
    const unsigned short* Bc = smem + 16384 + buf * 4096;
    __builtin_amdgcn_s_setprio(1);
#pragma unroll
    for (int kk = 0; kk < 64; kk += 32) {
      s16x8 av[2], bv[2];
#pragma unroll
      for (int f = 0; f < 2; ++f)
        av[f] = *(const s16x8*)(Ac + ((a_base + f * 1024 + kk) ^ akey));
#pragma unroll
      for (int f = 0; f < 2; ++f)
        bv[f] = *(const s16x8*)(Bc + ((b_base + f * 1024 + kk) ^ akey));
#pragma unroll
      for (int i = 0; i < 2; ++i)
#pragma unroll
        for (int j = 0; j < 2; ++j)
          acc[i][j] = __builtin_amdgcn_mfma_f32_16x16x32_bf16(av[i], bv[j], acc[i][j], 0, 0, 0);
    }
    __builtin_amdgcn_s_setprio(0);
  };
  loadB(0);
  issueA(0, 0);
  writeB(0);
  __syncthreads();
  for (int t = 0; t < 63; ++t) {
    int cur = t & 1, nxt = cur ^ 1;
    loadB((t + 1) * 16);
    issueA(nxt, (t + 1) * 64);
    compute(cur);
    writeB(nxt);
    __syncthreads();
  }
  loadF();
  compute(1);
  writeF(0);
  __syncthreads();
  compute(0);
#pragma unroll
  for (int fn = 0; fn < 2; ++fn) {
    int c = wn * 32 + fn * 16 + (lane & 15);
    int o = (c < 32) ? (o0 + c) : (HALF + o0 + (c - 32));
    float bv = bias[o];
#pragma unroll
    for (int fm = 0; fm < 2; ++fm) {
      int m = m0 + wm * 32 + fm * 16 + ((lane >> 4) << 2);
#pragma unroll
      for (int j = 0; j < 4; ++j)
        out[(size_t)(m + j) * OUT_F + o] = acc[fm][fn][j] + bv;
    }
  }
}

extern "C" void kernel_launch(void* const* d_in, const int* in_sizes, int n_in,
                              void* d_out, int out_size, void* d_ws, size_t ws_size,
                              hipStream_t stream) {
  const float* x     = (const float*)d_in[0];
  const int*   Wq    = (const int*)d_in[1];
  const float* scale = (const float*)d_in[2];
  const float* zero  = (const float*)d_in[3];
  const float* U     = (const float*)d_in[4];
  const float* V     = (const float*)d_in[5];
  const float* bias  = (const float*)d_in[6];
  float* out = (float*)d_out;

  unsigned short* xbf = (unsigned short*)d_ws;                 // 4 MB
  unsigned short* Ubf = xbf + (size_t)MROWS * IN_F;            // 704 KB
  float*          P   = (float*)(Ubf + (size_t)OUT_F * 32);    // 64 KB
  char*           rest = (char*)(P + (size_t)MROWS * 32);
  const size_t base   = (size_t)MROWS * IN_F * 2 + (size_t)OUT_F * 32 * 2
                      + (size_t)MROWS * 32 * 4;                // 4,964,352
  const size_t wbf_sz = (size_t)OUT_F * IN_F * 2;              // 90,177,536

  (void)hipMemsetAsync(P, 0, (size_t)MROWS * 32 * sizeof(float), stream);
  convert_k<<<2392, 256, 0, stream>>>(x, U, xbf, Ubf);
  pcalc_k<<<512, 256, 0, stream>>>(x, V, P);

  if (ws_size >= base + wbf_sz) {
    // ---- fast path: streaming dequant + T4-pipelined bf16 GEMM (r18 best)
    unsigned short* Wbf = (unsigned short*)rest;
    wdeq_k<<<5504, 256, 0, stream>>>((const i32x4*)Wq, scale, zero, Wbf);
    gemm_fast<<<688, 512, 73728, stream>>>(xbf, Wbf, P, (const i32x4*)Ubf,
                                           bias, out);
  } else {
    // ---- slow path: round-8 fused dequant GEMM (known-good)
    float* mz = (float*)rest;
    mz_k<<<688, 256, 0, stream>>>(scale, zero, (f32x4*)mz);
    milo_gemm<<<688, 512, 49152, stream>>>(xbf, (const i32x4*)Wq,
                                           (const f32x4*)scale, (const f32x4*)mz,
                                           P, (const i32x4*)Ubf, bias, out);
  }
}